// Round 2
// baseline (270.325 us; speedup 1.0000x reference)
//
#include <hip/hip_runtime.h>

#define B 4
#define N 2048
#define V 12
#define C 50
#define P 16384   // 128*128

// ---------------------------------------------------------------------------
// Kernel 1: one streaming pass over predictions_2d.
//  - per-pixel argmax over C (for the scatter key)
//  - per-pixel sum of exp(logit) over C (softmax denominator; logits are
//    N(0,1) so |l| < ~6 and unnormalized exp is exact in f32)
//  - masked atomicMax scatter of key = argmax*P + pixel into winner[b,v,n]
// 4 pixels/thread via float4; every c-pass is fully coalesced.
// ---------------------------------------------------------------------------
__global__ __launch_bounds__(256) void k1_argmax_scatter(
    const float4* __restrict__ predv,    // (B*V, C, P/4)
    const int4*  __restrict__ p2pv,      // (B*V, P/4)
    const int*   __restrict__ parts_nb,  // (B,)
    int*         __restrict__ winner,    // (B*V, N), pre-init -1
    float4*      __restrict__ sexp) {    // (B*V, P/4) sum-of-exp per pixel
  const int PQ = P / 4;
  int t = blockIdx.x * 256 + threadIdx.x;
  if (t >= B * V * PQ) return;
  int q  = t % PQ;
  int bv = t / PQ;
  int b  = bv / V;

  size_t base = (size_t)bv * C * PQ + q;
  float4 x = predv[base];
  float m0 = x.x, m1 = x.y, m2 = x.z, m3 = x.w;
  float s0 = __expf(x.x), s1 = __expf(x.y), s2 = __expf(x.z), s3 = __expf(x.w);
  int   a0 = 0,  a1 = 0,  a2 = 0,  a3 = 0;
  for (int c = 1; c < C; ++c) {
    float4 y = predv[base + (size_t)c * PQ];
    if (y.x > m0) { m0 = y.x; a0 = c; }
    if (y.y > m1) { m1 = y.y; a1 = c; }
    if (y.z > m2) { m2 = y.z; a2 = c; }
    if (y.w > m3) { m3 = y.w; a3 = c; }
    s0 += __expf(y.x); s1 += __expf(y.y);
    s2 += __expf(y.z); s3 += __expf(y.w);
  }
  sexp[(size_t)bv * PQ + q] = make_float4(s0, s1, s2, s3);

  int4 pt = p2pv[(size_t)bv * PQ + q];
  int pn = parts_nb[b];
  int p0 = q * 4;
  int* wbase = winner + bv * N;
  if (pt.x != -1 && a0 >= 1 && a0 <= pn) atomicMax(wbase + pt.x, a0 * P + p0);
  if (pt.y != -1 && a1 >= 1 && a1 <= pn) atomicMax(wbase + pt.y, a1 * P + p0 + 1);
  if (pt.z != -1 && a2 >= 1 && a2 <= pn) atomicMax(wbase + pt.z, a2 * P + p0 + 2);
  if (pt.w != -1 && a3 >= 1 && a3 <= pn) atomicMax(wbase + pt.w, a3 * P + p0 + 3);
}

// ---------------------------------------------------------------------------
// Kernel 2: one wave per (b,n). All 12 winner loads hoisted (independent),
// then 12 fully-predicated independent gather chains:
//   acc_c += exp(l_c) * vw_v / sexp[wp]     (no cross-lane reductions at all)
// ---------------------------------------------------------------------------
__global__ __launch_bounds__(256) void k2_gather(
    const float* __restrict__ pred,     // (B*V, C, P)
    const int*   __restrict__ winner,   // (B*V, N)
    const float* __restrict__ sexp,     // (B*V, P)
    const float* __restrict__ vw,       // (B*V,)
    float*       __restrict__ out) {    // (B, C, N)
  int wid  = blockIdx.x * (256 / 64) + (threadIdx.x >> 6);
  int lane = threadIdx.x & 63;
  int b = wid >> 11;        // N = 2048
  int n = wid & (N - 1);

  int wv[V];
  #pragma unroll
  for (int v = 0; v < V; ++v) wv[v] = winner[(b * V + v) * N + n];

  float acc = 0.f;
  int cnt = 0;
  #pragma unroll
  for (int v = 0; v < V; ++v) {
    bool valid = wv[v] >= 0;
    int wp = valid ? (wv[v] & (P - 1)) : 0;
    size_t bvo = (size_t)(b * V + v);
    float l = (lane < C) ? pred[(bvo * C + lane) * P + wp] : 0.f;
    float s = sexp[bvo * P + wp];
    float w = vw[b * V + v] / s;
    cnt += valid ? 1 : 0;
    acc += valid ? __expf(l) * w : 0.f;
  }
  float denom = (float)(cnt > 0 ? cnt : 1);
  if (lane < C)
    out[((size_t)b * C + lane) * N + n] = acc / denom;
}

extern "C" void kernel_launch(void* const* d_in, const int* in_sizes, int n_in,
                              void* d_out, int out_size, void* d_ws, size_t ws_size,
                              hipStream_t stream) {
  const float* pred  = (const float*)d_in[1];
  const int*   p2p   = (const int*)d_in[2];
  const float* vw    = (const float*)d_in[3];
  const int*   parts = (const int*)d_in[4];
  float* out = (float*)d_out;

  int*   winner = (int*)d_ws;                         // B*V*N ints = 384 KiB
  float* sexp   = (float*)((char*)d_ws + (size_t)B * V * N * sizeof(int)); // 3 MiB

  hipMemsetAsync(winner, 0xFF, (size_t)B * V * N * sizeof(int), stream);

  int nthreads1 = B * V * (P / 4);                    // 196608
  k1_argmax_scatter<<<(nthreads1 + 255) / 256, 256, 0, stream>>>(
      (const float4*)pred, (const int4*)p2p, parts, winner, (float4*)sexp);

  k2_gather<<<(B * N) / 4, 256, 0, stream>>>(pred, winner, sexp, vw, out);
}

// Round 3
// 259.838 us; speedup vs baseline: 1.0404x; 1.0404x over previous
//
#include <hip/hip_runtime.h>

#define B 4
#define N 2048
#define V 12
#define C 50
#define P 16384      // 128*128 = 2^14
#define CP 64        // padded C stride in wfeat (256 B aligned per winner)

// ---------------------------------------------------------------------------
// Kernel 1: per-pixel argmax over C + masked atomicMax scatter of
// key = argmax*P + pixel into winner[b,v,n]. 4 pixels/thread via float4.
// ---------------------------------------------------------------------------
__global__ __launch_bounds__(256) void k1_argmax_scatter(
    const float4* __restrict__ predv,    // (B*V, C, P/4)
    const int4*  __restrict__ p2pv,      // (B*V, P/4)
    const int*   __restrict__ parts_nb,  // (B,)
    int*         __restrict__ winner) {  // (B*V, N), pre-init -1
  const int PQ = P / 4;
  int t = blockIdx.x * 256 + threadIdx.x;
  if (t >= B * V * PQ) return;
  int q  = t % PQ;
  int bv = t / PQ;
  int b  = bv / V;

  size_t base = (size_t)bv * C * PQ + q;
  float4 x = predv[base];
  float m0 = x.x, m1 = x.y, m2 = x.z, m3 = x.w;
  int   a0 = 0,  a1 = 0,  a2 = 0,  a3 = 0;
  for (int c = 1; c < C; ++c) {
    float4 y = predv[base + (size_t)c * PQ];
    if (y.x > m0) { m0 = y.x; a0 = c; }
    if (y.y > m1) { m1 = y.y; a1 = c; }
    if (y.z > m2) { m2 = y.z; a2 = c; }
    if (y.w > m3) { m3 = y.w; a3 = c; }
  }

  int4 pt = p2pv[(size_t)bv * PQ + q];
  int pn = parts_nb[b];
  int p0 = q * 4;
  int* wbase = winner + bv * N;
  if (pt.x != -1 && a0 >= 1 && a0 <= pn) atomicMax(wbase + pt.x, a0 * P + p0);
  if (pt.y != -1 && a1 >= 1 && a1 <= pn) atomicMax(wbase + pt.y, a1 * P + p0 + 1);
  if (pt.z != -1 && a2 >= 1 && a2 <= pn) atomicMax(wbase + pt.z, a2 * P + p0 + 2);
  if (pt.w != -1 && a3 >= 1 && a3 <= pn) atomicMax(wbase + pt.w, a3 * P + p0 + 3);
}

// ---------------------------------------------------------------------------
// Kernel 1b: one pixel per thread. A pixel is THE winner for (bv, n=p2p[p])
// iff winner[bv][n] >= 0 and its pixel field equals p (keys encode the pixel
// uniquely, and only mask-passing pixels ever scattered). Winner lanes stream
// their 50 logits (lane-consecutive addresses -> dense lines, L3-resident
// after k1), compute vw * softmax locally, write 50 floats contiguously.
// ---------------------------------------------------------------------------
__global__ __launch_bounds__(256) void k1b_extract(
    const float* __restrict__ pred,     // (B*V, C, P)
    const int*   __restrict__ p2p,      // (B*V, P)
    const int*   __restrict__ winner,   // (B*V, N)
    const float* __restrict__ vw,       // (B*V,)
    float*       __restrict__ wfeat) {  // (B*V*N, CP)
  int t = blockIdx.x * 256 + threadIdx.x;   // t < B*V*P
  int p  = t & (P - 1);
  int bv = t >> 14;                          // P = 2^14

  int pt = p2p[(size_t)bv * P + p];
  if (pt == -1) return;
  int bvn = bv * N + pt;
  int key = winner[bvn];
  if (key < 0 || (key & (P - 1)) != p) return;   // not the winner pixel

  const float* pp = pred + (size_t)bv * C * P + p;
  float e[C];
  float s = 0.f;
  #pragma unroll
  for (int c = 0; c < C; ++c) e[c] = pp[(size_t)c * P];
  #pragma unroll
  for (int c = 0; c < C; ++c) { e[c] = __expf(e[c]); s += e[c]; }
  float w = vw[bv] / s;

  float4* dst = (float4*)(wfeat + (size_t)bvn * CP);
  #pragma unroll
  for (int c4 = 0; c4 < C / 4; ++c4) {       // 12 float4 stores (48 floats)
    dst[c4] = make_float4(e[4*c4] * w, e[4*c4+1] * w, e[4*c4+2] * w, e[4*c4+3] * w);
  }
  wfeat[(size_t)bvn * CP + 48] = e[48] * w;
  wfeat[(size_t)bvn * CP + 49] = e[49] * w;
}

// ---------------------------------------------------------------------------
// Kernel 3: one wave per (b,n). Lanes 0..49 read wfeat coalesced (4 aligned
// lines per (v,n)), sum valid views, divide by count, store out[b,c,n].
// ---------------------------------------------------------------------------
__global__ __launch_bounds__(256) void k3_reduce(
    const int*   __restrict__ winner,   // (B*V, N)
    const float* __restrict__ wfeat,    // (B*V*N, CP)
    float*       __restrict__ out) {    // (B, C, N)
  int wid  = blockIdx.x * 4 + (threadIdx.x >> 6);
  int lane = threadIdx.x & 63;
  int b = wid >> 11;                    // N = 2048
  int n = wid & (N - 1);

  float acc = 0.f;
  int cnt = 0;
  #pragma unroll
  for (int v = 0; v < V; ++v) {
    int bvn = (b * V + v) * N + n;
    bool valid = winner[bvn] >= 0;
    float f = (valid && lane < C) ? wfeat[(size_t)bvn * CP + lane] : 0.f;
    cnt += valid ? 1 : 0;
    acc += f;
  }
  if (lane < C)
    out[((size_t)b * C + lane) * N + n] = acc / (float)(cnt > 0 ? cnt : 1);
}

extern "C" void kernel_launch(void* const* d_in, const int* in_sizes, int n_in,
                              void* d_out, int out_size, void* d_ws, size_t ws_size,
                              hipStream_t stream) {
  const float* pred  = (const float*)d_in[1];
  const int*   p2p   = (const int*)d_in[2];
  const float* vw    = (const float*)d_in[3];
  const int*   parts = (const int*)d_in[4];
  float* out = (float*)d_out;

  int*   winner = (int*)d_ws;                               // 384 KiB
  float* wfeat  = (float*)((char*)d_ws + (size_t)B * V * N * sizeof(int)); // 24 MiB

  hipMemsetAsync(winner, 0xFF, (size_t)B * V * N * sizeof(int), stream);

  int nthreads1 = B * V * (P / 4);                          // 196608
  k1_argmax_scatter<<<(nthreads1 + 255) / 256, 256, 0, stream>>>(
      (const float4*)pred, (const int4*)p2p, parts, winner);

  int nthreads1b = B * V * P;                               // 786432
  k1b_extract<<<nthreads1b / 256, 256, 0, stream>>>(
      pred, p2p, winner, vw, wfeat);

  k3_reduce<<<(B * N) / 4, 256, 0, stream>>>(winner, wfeat, out);
}